// Round 10
// baseline (1005.900 us; speedup 1.0000x reference)
//
#include <hip/hip_runtime.h>
#include <math.h>

#define BATCH 256
#define SEQ 512
#define SDS 54            // floats per (b,t) record: dt[6] cos[6] sin[6] Cc[18] term[18]
#define PI_F 3.14159265358979323846f
#define INV2PI 0.15915494309189535f

// ---- cross-lane helpers -----------------------------------------------------
template<int CTRL>
__device__ __forceinline__ float fdpp(float v) {
    return __int_as_float(__builtin_amdgcn_mov_dpp(__float_as_int(v), CTRL, 0xF, 0xF, true));
}
template<int L>
__device__ __forceinline__ float rdl(float v) {
    return __int_as_float(__builtin_amdgcn_readlane(__float_as_int(v), L));
}
__device__ __forceinline__ float rdlv(float v, int l) {
    return __int_as_float(__builtin_amdgcn_readlane(__float_as_int(v), l));
}
template<int M>
__device__ __forceinline__ float shxm(float v) {
    if constexpr (M == 1)       return fdpp<0xB1>(v);
    else if constexpr (M == 2)  return fdpp<0x4E>(v);
    else if constexpr (M == 8)  return fdpp<0x128>(v);
    else if constexpr (M == 32) return __shfl_xor(v, 32, 64);
    else return __int_as_float(__builtin_amdgcn_ds_swizzle(__float_as_int(v), (M << 10) | 0x1F));
}
// full 64-lane sum (uniform result): DPP row_ror rotate-adds + readlane combine
__device__ __forceinline__ float redsum64(float v) {
    v += fdpp<0x128>(v);
    v += fdpp<0x124>(v);
    v += fdpp<0x122>(v);
    v += fdpp<0x121>(v);
    return (rdl<0>(v) + rdl<16>(v)) + (rdl<32>(v) + rdl<48>(v));
}
__device__ __forceinline__ float xorf(float v, int m) {
    return __int_as_float(__float_as_int(v) ^ m);
}
// native HW sincos: v_sin/v_cos take input in revolutions. All loop angles are
// |x| << 1 rev (phi ~ 0.1, h in [-1,1]) — in the HW-exact domain. Validated R9.
__device__ __forceinline__ void nsincos(float x, float& s, float& c) {
    float r = x * INV2PI;
    s = __builtin_amdgcn_sinf(r);
    c = __builtin_amdgcn_cosf(r);
}
// Workgroup barrier with LDS-only drain (lgkmcnt(0)); global ops stay in flight.
__device__ __forceinline__ void wg_barrier_lds() {
    __builtin_amdgcn_sched_barrier(0);
    __builtin_amdgcn_s_waitcnt(0xC07F);
    __builtin_amdgcn_s_barrier();
    __builtin_amdgcn_sched_barrier(0);
}
// QSVT per-degree CNOT-block permutation (GF(2)-linear) — verified R1-R9
__device__ __forceinline__ int permf(int x) {
    const int cs[11] = {0,1,2,3,4,5,5,4,3,2,1};
    const int ts[11] = {1,2,3,4,5,0,4,3,2,1,0};
#pragma unroll
    for (int k = 10; k >= 0; k--) {
        int cb = (x >> (5 - cs[k])) & 1;
        x ^= cb << (5 - ts[k]);
    }
    return x;
}
__device__ __forceinline__ void cmul4(const float* c,
    float vr, float vi, float ar, float ai, float br, float bi, float cr, float ci,
    float& nr, float& ni) {
    nr = c[0]*vr - c[1]*vi + c[2]*ar - c[3]*ai + c[4]*br - c[5]*bi + c[6]*cr - c[7]*ci;
    ni = c[0]*vi + c[1]*vr + c[2]*ai + c[3]*ar + c[4]*bi + c[5]*br + c[6]*ci + c[7]*cr;
}
__device__ __forceinline__ void ringapply(const float* rc,
    float vr, float vi, float br, float bi, float cr, float ci, float dr, float di,
    float& nr, float& ni) {
    nr = rc[0]*vr - rc[1]*bi - rc[2]*ci + rc[3]*dr;
    ni = rc[0]*vi + rc[1]*br + rc[2]*cr + rc[3]*di;
}

// ---------------------------------------------------------------------------
__global__ __launch_bounds__(256) void prep_kernel(
    const float* __restrict__ angles, const float* __restrict__ Wx,
    const float* __restrict__ Wdt, const float* __restrict__ bdt,
    const float* __restrict__ D, const float* __restrict__ Wc,
    float* __restrict__ sd)
{
    int gid = blockIdx.x * blockDim.x + threadIdx.x;
    if (gid >= BATCH * SEQ) return;
    const float* a = angles + (size_t)gid * 6;
    float ang[6];
#pragma unroll
    for (int i = 0; i < 6; i++) ang[i] = a[i];
    float dtr[3];
#pragma unroll
    for (int r = 0; r < 3; r++) {
        float s = 0.f;
#pragma unroll
        for (int k = 0; k < 6; k++) s += ang[k] * Wx[r * 6 + k];
        dtr[r] = s;
    }
    float* rec = sd + (size_t)gid * SDS;
    float dtv[6];
#pragma unroll
    for (int i = 0; i < 6; i++) {
        float x = bdt[i];
#pragma unroll
        for (int r = 0; r < 3; r++) x += dtr[r] * Wdt[i * 3 + r];
        float sp = (x > 15.f) ? x : log1pf(expf(x));
        dtv[i] = tanhf(sp) * PI_F;
        rec[i] = dtv[i];
        float th = ang[i] * dtv[i];
        rec[6 + i]  = cosf(th);
        rec[12 + i] = sinf(th);
    }
    float C[6];
#pragma unroll
    for (int i = 0; i < 6; i++) {
        float s = 0.f;
#pragma unroll
        for (int k = 0; k < 6; k++) s += ang[k] * Wx[(9 + i) * 6 + k];
        C[i] = s;
    }
#pragma unroll
    for (int j = 0; j < 18; j++) {
        float s = 0.f;
#pragma unroll
        for (int i = 0; i < 6; i++) s += C[i] * Wc[j * 6 + i];
        rec[18 + j] = s;
        rec[36 + j] = D[j] * ang[j % 6];
    }
}

// ---------------------------------------------------------------------------
// umat_kernel: U[a][col] for the fixed 2-layer ansatz (R2-verified gate chain).
// ---------------------------------------------------------------------------
__global__ __launch_bounds__(64) void umat_kernel(const float* __restrict__ cp,
                                                  float2* __restrict__ um)
{
    const int lane = threadIdx.x;
    const int col = blockIdx.x;
    int bitv[6];
#pragma unroll
    for (int i = 0; i < 6; i++) bitv[i] = (lane >> (5 - i)) & 1;

    float qc[2][3][8], rc[2][6][4];
#pragma unroll
    for (int l = 0; l < 2; l++) {
        float g00r[6], g00i[6], g01r[6], g01i[6], g10r[6], g10i[6], g11r[6], g11i[6];
#pragma unroll
        for (int i = 0; i < 6; i++) {
            float ax = cp[l * 30 + i * 3 + 0];
            float ay = cp[l * 30 + i * 3 + 1];
            float az = cp[l * 30 + i * 3 + 2];
            float ca = cosf(0.5f * ax), sa = sinf(0.5f * ax);
            float cb = cosf(0.5f * ay), sb = sinf(0.5f * ay);
            float cg = cosf(0.5f * az), sg = sinf(0.5f * az);
            float m00r = cb * ca, m00i =  sb * sa;
            float m01r = -sb * ca, m01i = -cb * sa;
            float m10r =  sb * ca, m10i = -cb * sa;
            float m11r =  cb * ca, m11i = -sb * sa;
            g00r[i] = cg * m00r + sg * m00i; g00i[i] = cg * m00i - sg * m00r;
            g01r[i] = cg * m01r + sg * m01i; g01i[i] = cg * m01i - sg * m01r;
            g10r[i] = cg * m10r - sg * m10i; g10i[i] = cg * m10i + sg * m10r;
            g11r[i] = cg * m11r - sg * m11i; g11i[i] = cg * m11i + sg * m11r;
        }
#pragma unroll
        for (int pp = 0; pp < 3; pp++) {
            int aq = 2 * pp, bq = 2 * pp + 1;
            float dar = bitv[aq] ? g11r[aq] : g00r[aq], dai = bitv[aq] ? g11i[aq] : g00i[aq];
            float oar = bitv[aq] ? g10r[aq] : g01r[aq], oai = bitv[aq] ? g10i[aq] : g01i[aq];
            float dbr = bitv[bq] ? g11r[bq] : g00r[bq], dbi = bitv[bq] ? g11i[bq] : g00i[bq];
            float obr = bitv[bq] ? g10r[bq] : g01r[bq], obi = bitv[bq] ? g10i[bq] : g01i[bq];
            qc[l][pp][0] = dar * dbr - dai * dbi;  qc[l][pp][1] = dar * dbi + dai * dbr;
            qc[l][pp][2] = oar * dbr - oai * dbi;  qc[l][pp][3] = oar * dbi + oai * dbr;
            qc[l][pp][4] = dar * obr - dai * obi;  qc[l][pp][5] = dar * obi + dai * obr;
            qc[l][pp][6] = oar * obr - oai * obi;  qc[l][pp][7] = oar * obi + oai * obr;
        }
        const int Aq[6] = {0, 2, 4, 5, 3, 1};
        const int Bq[6] = {1, 3, 5, 4, 2, 0};
#pragma unroll
        for (int o = 0; o < 6; o++) {
            float tha = (o < 3) ? cp[l * 30 + 18 + 2 * o]     : cp[l * 30 + 24 + 2 * (o - 3)];
            float thb = (o < 3) ? cp[l * 30 + 18 + 2 * o + 1] : cp[l * 30 + 24 + 2 * (o - 3) + 1];
            float ca = cosf(0.5f * tha), sa = sinf(0.5f * tha);
            float cb = cosf(0.5f * thb), sb = sinf(0.5f * thb);
            int ba = bitv[Aq[o]], bb = bitv[Bq[o]];
            float mx0 = ba ? ca : 1.f, sae = ba ? sa : 0.f;
            float ny0 = bb ? cb : 1.f, sbe = bb ? sb : 0.f;
            rc[l][o][0] = ny0 * mx0; rc[l][o][1] = -ny0 * sae;
            rc[l][o][2] = -mx0 * sbe; rc[l][o][3] = -sae * sbe;
        }
    }

    float re = (lane == col) ? 1.f : 0.f;
    float im = 0.f;
    auto p1q = [&](int mi, int mj, const float* c) {
        float ar = __shfl_xor(re, mi, 64), ai = __shfl_xor(im, mi, 64);
        float br = __shfl_xor(re, mj, 64), bi = __shfl_xor(im, mj, 64);
        float cr = __shfl_xor(re, mi | mj, 64), ci = __shfl_xor(im, mi | mj, 64);
        float nr, ni;
        cmul4(c, re, im, ar, ai, br, bi, cr, ci, nr, ni);
        re = nr; im = ni;
    };
    auto rng = [&](int mb, int mc, const float* c) {
        float br = __shfl_xor(re, mb, 64), bi = __shfl_xor(im, mb, 64);
        float cr = __shfl_xor(re, mc, 64), ci = __shfl_xor(im, mc, 64);
        float dr = __shfl_xor(re, mb | mc, 64), di = __shfl_xor(im, mb | mc, 64);
        float nr, ni;
        ringapply(c, re, im, br, bi, cr, ci, dr, di, nr, ni);
        re = nr; im = ni;
    };
#pragma unroll
    for (int l = 0; l < 2; l++) {
        p1q(32, 16, qc[l][0]);
        p1q(8, 4, qc[l][1]);
        p1q(2, 1, qc[l][2]);
        rng(16, 8, rc[l][0]);
        rng(4, 2, rc[l][1]);
        rng(1, 32, rc[l][2]);
        rng(2, 4, rc[l][3]);
        rng(8, 16, rc[l][4]);
        rng(32, 1, rc[l][5]);
    }
    um[(size_t)lane * 64 + col] = make_float2(re, im);
}

// ---------------------------------------------------------------------------
// step_kernel: R7's proven 4-wave / 2-barrier structure with:
//  - native v_sin/v_cos in the loop
//  - balanced reductions: w0 Z0-3 | w1 Z4,Z5,X0,X1 | w2 X2-5 | w3 Y0-5 deferred
//  - all store-side record fields software-prefetched
// ---------------------------------------------------------------------------
__global__ __launch_bounds__(256, 1) void step_kernel(
    const float* __restrict__ sd, const float* __restrict__ pc,
    const float* __restrict__ qp, const float2* __restrict__ um,
    float* __restrict__ out)
{
    __shared__ float2 sPart[4][64];
    __shared__ __align__(16) float sZX[12];   // Z0..5, X0..5
    const int tid = threadIdx.x;
    const int wave = tid >> 6;
    const int lane = tid & 63;
    const int b = blockIdx.x;

    int bitv[6];
#pragma unroll
    for (int i = 0; i < 6; i++) bitv[i] = (lane >> (5 - i)) & 1;
    int sflip[6];
#pragma unroll
    for (int q = 0; q < 6; q++) sflip[q] = bitv[q] ? (int)0x80000000 : 0;

    // U column-chunk rows: wave w owns columns [16w, 16w+16)
    const int jbase = wave * 16;
    float2 row[16];
#pragma unroll
    for (int jj = 0; jj < 16; jj++) row[jj] = um[(size_t)lane * 64 + jbase + jj];

    // QSVT collapse: per-lane phase coefs + permuted product-state selects
    float A[6], sel[6];
    {
        int x1 = permf(lane), x2 = permf(x1), x3 = permf(x2), x4 = permf(x3);
#pragma unroll
        for (int i = 0; i < 6; i++) {
            float u0 = pc[0] * PI_F * qp[0 * 6 + i];
            float u1 = pc[1] * PI_F * qp[1 * 6 + i];
            float u2 = pc[2] * PI_F * qp[2 * 6 + i];
            float u3 = pc[3] * PI_F;
            float t1 = ((x1 >> (5 - i)) & 1) ? 0.5f : -0.5f;
            float t2 = ((x2 >> (5 - i)) & 1) ? 0.5f : -0.5f;
            float t3 = ((x3 >> (5 - i)) & 1) ? 0.5f : -0.5f;
            float t4 = ((x4 >> (5 - i)) & 1) ? 0.5f : -0.5f;
            A[i] = u3 * t1 + u2 * t2 + u1 * t3 + u0 * t4;
            sel[i] = (float)((x4 >> (5 - i)) & 1);
        }
    }

    const float* sdb = sd + (size_t)b * SEQ * SDS;
    float* outb = out + (size_t)b * SEQ * 18;

    float h0 = 0.f, h1 = 0.f, h2 = 0.f, h3 = 0.f, h4 = 0.f, h5 = 0.f;

    // pipelined record fields
    float cd[18], nd[18];                 // fields 0-17 (all waves)
    float zf[12], zfn[12];                // w0: fields 30-35, 48-53 (Z store)
    float wf[24], wfn[24], pwf[24];       // w3: fields 18-29, 36-47 (X/Y store)
    float ysv[6], px[6];                  // w3: deferred Y pair-sums, saved px
#pragma unroll
    for (int q = 0; q < 6; q++) { ysv[q] = 0.f; px[q] = 0.f; }
#pragma unroll
    for (int k = 0; k < 18; k++) cd[k] = sdb[k];
    if (wave == 0) {
#pragma unroll
        for (int j = 0; j < 6; j++) { zf[j] = sdb[30 + j]; zf[6 + j] = sdb[48 + j]; }
    }
    if (wave == 3) {
#pragma unroll
        for (int j = 0; j < 12; j++) { wf[j] = sdb[18 + j]; wf[12 + j] = sdb[36 + j]; }
    }

    for (int t = 0; t < SEQ; t++) {
        const float* rn = sdb + (size_t)((t + 1 < SEQ) ? t + 1 : t) * SDS;
        // prefetch record t+1 (stays in flight across lgkm-only barriers)
#pragma unroll
        for (int k = 0; k < 18; k++) nd[k] = rn[k];
        if (wave == 0) {
#pragma unroll
            for (int j = 0; j < 6; j++) { zfn[j] = rn[30 + j]; zfn[6 + j] = rn[48 + j]; }
        }
        if (wave == 3) {
#pragma unroll
            for (int j = 0; j < 12; j++) { wfn[j] = rn[18 + j]; wfn[12 + j] = rn[36 + j]; }
        }

        // ---- w3 pre-barrier: deferred Y(t-1) + X/Y stores of t-1 ----
        if (wave == 3 && t > 0) {
            float Y0 = redsum64(ysv[0]), Y1 = redsum64(ysv[1]), Y2 = redsum64(ysv[2]);
            float Y3 = redsum64(ysv[3]), Y4 = redsum64(ysv[4]), Y5 = redsum64(ysv[5]);
            if (lane == 0) {
                float Yv[6] = {Y0, Y1, Y2, Y3, Y4, Y5};
                float* o = outb + (size_t)(t - 1) * 18;
#pragma unroll
                for (int q = 0; q < 6; q++) {
                    o[q]     = fmaf(pwf[q],     px[q], pwf[12 + q]);
                    o[6 + q] = fmaf(pwf[6 + q], Yv[q], pwf[18 + q]);
                }
            }
        }

        // ---- QSVT phase (h-independent) ----
        float phi = A[0]*cd[0] + A[1]*cd[1] + A[2]*cd[2] + A[3]*cd[3] + A[4]*cd[4] + A[5]*cd[5];
        float sph, cph;
        nsincos(phi, sph, cph);

        // ---- product state RY(h)|0..0>, pre-permuted via sel bits ----
        float ss0, cc0, ss1, cc1, ss2, cc2, ss3, cc3, ss4, cc4, ss5, cc5;
        nsincos(0.5f * h0, ss0, cc0);
        nsincos(0.5f * h1, ss1, cc1);
        nsincos(0.5f * h2, ss2, cc2);
        nsincos(0.5f * h3, ss3, cc3);
        nsincos(0.5f * h4, ss4, cc4);
        nsincos(0.5f * h5, ss5, cc5);
        float f0 = fmaf(sel[0], ss0 - cc0, cc0);
        float f1 = fmaf(sel[1], ss1 - cc1, cc1);
        float f2 = fmaf(sel[2], ss2 - cc2, cc2);
        float f3 = fmaf(sel[3], ss3 - cc3, cc3);
        float f4 = fmaf(sel[4], ss4 - cc4, cc4);
        float f5 = fmaf(sel[5], ss5 - cc5, cc5);
        float prod = ((f0 * f1) * (f2 * f3)) * (f4 * f5);
        float pr = prod * cph, pi = prod * sph;

        // ---- partial matvec over this wave's 16 columns ----
        float ar0 = 0.f, ai0 = 0.f, ar1 = 0.f, ai1 = 0.f;
#pragma unroll
        for (int jj = 0; jj < 16; jj += 2) {
            float sr0 = rdlv(pr, jbase + jj);
            float si0 = rdlv(pi, jbase + jj);
            float sr1 = rdlv(pr, jbase + jj + 1);
            float si1 = rdlv(pi, jbase + jj + 1);
            ar0 = fmaf(row[jj].x, sr0, ar0);
            ar0 = fmaf(-row[jj].y, si0, ar0);
            ai0 = fmaf(row[jj].x, si0, ai0);
            ai0 = fmaf(row[jj].y, sr0, ai0);
            ar1 = fmaf(row[jj + 1].x, sr1, ar1);
            ar1 = fmaf(-row[jj + 1].y, si1, ar1);
            ai1 = fmaf(row[jj + 1].x, si1, ai1);
            ai1 = fmaf(row[jj + 1].y, sr1, ai1);
        }
        sPart[wave][lane] = make_float2(ar0 + ar1, ai0 + ai1);
        wg_barrier_lds();   // barrier A
        float2 q0v = sPart[0][lane], q1v = sPart[1][lane];
        float2 q2v = sPart[2][lane], q3v = sPart[3][lane];
        float re = (q0v.x + q1v.x) + (q2v.x + q3v.x);
        float im = (q0v.y + q1v.y) + (q2v.y + q3v.y);

        // ---- balanced reductions ----
        if (wave == 0) {
            float p = re * re + im * im;
            float Z0 = redsum64(xorf(p, sflip[0]));
            float Z1 = redsum64(xorf(p, sflip[1]));
            float Z2 = redsum64(xorf(p, sflip[2]));
            float Z3 = redsum64(xorf(p, sflip[3]));
            if (lane == 0) { sZX[0] = Z0; sZX[1] = Z1; sZX[2] = Z2; sZX[3] = Z3; }
        } else if (wave == 1) {
            float p = re * re + im * im;
            float Z4 = redsum64(xorf(p, sflip[4]));
            float Z5 = redsum64(xorf(p, sflip[5]));
            float g0r = shxm<32>(re), g0i = shxm<32>(im);
            float g1r = shxm<16>(re), g1i = shxm<16>(im);
            float X0 = redsum64(fmaf(re, g0r, im * g0i));
            float X1 = redsum64(fmaf(re, g1r, im * g1i));
            if (lane == 0) { sZX[4] = Z4; sZX[5] = Z5; sZX[6] = X0; sZX[7] = X1; }
        } else if (wave == 2) {
            float g2r = shxm<8>(re), g2i = shxm<8>(im);
            float g3r = shxm<4>(re), g3i = shxm<4>(im);
            float g4r = shxm<2>(re), g4i = shxm<2>(im);
            float g5r = shxm<1>(re), g5i = shxm<1>(im);
            float X2 = redsum64(fmaf(re, g2r, im * g2i));
            float X3 = redsum64(fmaf(re, g3r, im * g3i));
            float X4 = redsum64(fmaf(re, g4r, im * g4i));
            float X5 = redsum64(fmaf(re, g5r, im * g5i));
            if (lane == 0) { sZX[8] = X2; sZX[9] = X3; sZX[10] = X4; sZX[11] = X5; }
        } else {
            // w3: pair products only (Y reduced next step, pre-barrier)
            float g0r = shxm<32>(re), g0i = shxm<32>(im);
            float g1r = shxm<16>(re), g1i = shxm<16>(im);
            float g2r = shxm<8>(re),  g2i = shxm<8>(im);
            float g3r = shxm<4>(re),  g3i = shxm<4>(im);
            float g4r = shxm<2>(re),  g4i = shxm<2>(im);
            float g5r = shxm<1>(re),  g5i = shxm<1>(im);
            ysv[0] = xorf(re * g0i - im * g0r, sflip[0]);
            ysv[1] = xorf(re * g1i - im * g1r, sflip[1]);
            ysv[2] = xorf(re * g2i - im * g2r, sflip[2]);
            ysv[3] = xorf(re * g3i - im * g3r, sflip[3]);
            ysv[4] = xorf(re * g4i - im * g4r, sflip[4]);
            ysv[5] = xorf(re * g5i - im * g5r, sflip[5]);
        }
        wg_barrier_lds();   // barrier B

        // ---- all waves: vectorized scalar broadcast, assemble h ----
        float4 v0 = ((const float4*)sZX)[0];   // Z0..Z3
        float4 v1 = ((const float4*)sZX)[1];   // Z4 Z5 X0 X1
        float4 v2 = ((const float4*)sZX)[2];   // X2..X5
        float Zv[6] = {v0.x, v0.y, v0.z, v0.w, v1.x, v1.y};
        float Xv[6] = {v1.z, v1.w, v2.x, v2.y, v2.z, v2.w};
        h0 = cd[6]  * Zv[0] - cd[12] * Xv[0];
        h1 = cd[7]  * Zv[1] - cd[13] * Xv[1];
        h2 = cd[8]  * Zv[2] - cd[14] * Xv[2];
        h3 = cd[9]  * Zv[3] - cd[15] * Xv[3];
        h4 = cd[10] * Zv[4] - cd[16] * Xv[4];
        h5 = cd[11] * Zv[5] - cd[17] * Xv[5];

        // ---- w0: Z store for step t (fields register-resident) ----
        if (wave == 0 && lane == 0) {
            float* o = outb + (size_t)t * 18;
            float hh[6] = {h0, h1, h2, h3, h4, h5};
#pragma unroll
            for (int q = 0; q < 6; q++) o[12 + q] = fmaf(zf[q], hh[q], zf[6 + q]);
        }
        // ---- w3: save px for deferred X store ----
        if (wave == 3) {
#pragma unroll
            for (int q = 0; q < 6; q++) px[q] = cd[6 + q] * Xv[q] + cd[12 + q] * Zv[q];
        }

        // rotate pipelined records
#pragma unroll
        for (int k = 0; k < 18; k++) cd[k] = nd[k];
        if (wave == 0) {
#pragma unroll
            for (int k = 0; k < 12; k++) zf[k] = zfn[k];
        }
        if (wave == 3) {
#pragma unroll
            for (int k = 0; k < 24; k++) { pwf[k] = wf[k]; wf[k] = wfn[k]; }
        }
    }

    // epilogue: w3 flushes Y + X/Y stores for t = SEQ-1 (pwf = record SEQ-1)
    if (wave == 3) {
        float Y0 = redsum64(ysv[0]), Y1 = redsum64(ysv[1]), Y2 = redsum64(ysv[2]);
        float Y3 = redsum64(ysv[3]), Y4 = redsum64(ysv[4]), Y5 = redsum64(ysv[5]);
        if (lane == 0) {
            float Yv[6] = {Y0, Y1, Y2, Y3, Y4, Y5};
            float* o = outb + (size_t)(SEQ - 1) * 18;
#pragma unroll
            for (int q = 0; q < 6; q++) {
                o[q]     = fmaf(pwf[q],     px[q], pwf[12 + q]);
                o[6 + q] = fmaf(pwf[6 + q], Yv[q], pwf[18 + q]);
            }
        }
    }
}

// ---------------------------------------------------------------------------
extern "C" void kernel_launch(void* const* d_in, const int* in_sizes, int n_in,
                              void* d_out, int out_size, void* d_ws, size_t ws_size,
                              hipStream_t stream) {
    const float* angles = (const float*)d_in[0];
    const float* Wx     = (const float*)d_in[1];
    const float* Wdt    = (const float*)d_in[2];
    const float* bdt    = (const float*)d_in[3];
    const float* pc     = (const float*)d_in[4];
    const float* qp     = (const float*)d_in[5];
    const float* cp     = (const float*)d_in[6];
    const float* D      = (const float*)d_in[7];
    const float* Wc     = (const float*)d_in[8];
    float* sd  = (float*)d_ws;                                // 28.3 MB
    float2* um = (float2*)(sd + (size_t)BATCH * SEQ * SDS);   // +32 KB
    float* out = (float*)d_out;

    umat_kernel<<<64, 64, 0, stream>>>(cp, um);
    prep_kernel<<<(BATCH * SEQ) / 256, 256, 0, stream>>>(angles, Wx, Wdt, bdt, D, Wc, sd);
    step_kernel<<<BATCH, 256, 0, stream>>>(sd, pc, qp, um, out);
}

// Round 11
// 975.215 us; speedup vs baseline: 1.0315x; 1.0315x over previous
//
#include <hip/hip_runtime.h>
#include <math.h>

#define BATCH 256
#define SEQ 512
#define SDS 54            // floats per (b,t) record: dt[6] cos[6] sin[6] Cc[18] term[18]
#define PI_F 3.14159265358979323846f

// ---- cross-lane helpers -----------------------------------------------------
template<int CTRL>
__device__ __forceinline__ float fdpp(float v) {
    return __int_as_float(__builtin_amdgcn_mov_dpp(__float_as_int(v), CTRL, 0xF, 0xF, true));
}
template<int L>
__device__ __forceinline__ float rdl(float v) {
    return __int_as_float(__builtin_amdgcn_readlane(__float_as_int(v), L));
}
__device__ __forceinline__ float rdlv(float v, int l) {
    return __int_as_float(__builtin_amdgcn_readlane(__float_as_int(v), l));
}
template<int M>
__device__ __forceinline__ float shxm(float v) {
    if constexpr (M == 1)       return fdpp<0xB1>(v);
    else if constexpr (M == 2)  return fdpp<0x4E>(v);
    else if constexpr (M == 8)  return fdpp<0x128>(v);
    else if constexpr (M == 32) return __shfl_xor(v, 32, 64);
    else return __int_as_float(__builtin_amdgcn_ds_swizzle(__float_as_int(v), (M << 10) | 0x1F));
}
// full 64-lane sum (uniform result): DPP row_ror rotate-adds + readlane combine
__device__ __forceinline__ float redsum64(float v) {
    v += fdpp<0x128>(v);
    v += fdpp<0x124>(v);
    v += fdpp<0x122>(v);
    v += fdpp<0x121>(v);
    return (rdl<0>(v) + rdl<16>(v)) + (rdl<32>(v) + rdl<48>(v));
}
__device__ __forceinline__ float xorf(float v, int m) {
    return __int_as_float(__float_as_int(v) ^ m);
}
// Workgroup barrier with LDS-only drain (lgkmcnt(0)); global ops stay in flight.
__device__ __forceinline__ void wg_barrier_lds() {
    __builtin_amdgcn_sched_barrier(0);
    __builtin_amdgcn_s_waitcnt(0xC07F);
    __builtin_amdgcn_s_barrier();
    __builtin_amdgcn_sched_barrier(0);
}
// QSVT per-degree CNOT-block permutation (GF(2)-linear) — verified R1-R10
__device__ __forceinline__ int permf(int x) {
    const int cs[11] = {0,1,2,3,4,5,5,4,3,2,1};
    const int ts[11] = {1,2,3,4,5,0,4,3,2,1,0};
#pragma unroll
    for (int k = 10; k >= 0; k--) {
        int cb = (x >> (5 - cs[k])) & 1;
        x ^= cb << (5 - ts[k]);
    }
    return x;
}
__device__ __forceinline__ void cmul4(const float* c,
    float vr, float vi, float ar, float ai, float br, float bi, float cr, float ci,
    float& nr, float& ni) {
    nr = c[0]*vr - c[1]*vi + c[2]*ar - c[3]*ai + c[4]*br - c[5]*bi + c[6]*cr - c[7]*ci;
    ni = c[0]*vi + c[1]*vr + c[2]*ai + c[3]*ar + c[4]*bi + c[5]*br + c[6]*ci + c[7]*cr;
}
__device__ __forceinline__ void ringapply(const float* rc,
    float vr, float vi, float br, float bi, float cr, float ci, float dr, float di,
    float& nr, float& ni) {
    nr = rc[0]*vr - rc[1]*bi - rc[2]*ci + rc[3]*dr;
    ni = rc[0]*vi + rc[1]*br + rc[2]*cr + rc[3]*di;
}

// ---------------------------------------------------------------------------
__global__ __launch_bounds__(256) void prep_kernel(
    const float* __restrict__ angles, const float* __restrict__ Wx,
    const float* __restrict__ Wdt, const float* __restrict__ bdt,
    const float* __restrict__ D, const float* __restrict__ Wc,
    float* __restrict__ sd)
{
    int gid = blockIdx.x * blockDim.x + threadIdx.x;
    if (gid >= BATCH * SEQ) return;
    const float* a = angles + (size_t)gid * 6;
    float ang[6];
#pragma unroll
    for (int i = 0; i < 6; i++) ang[i] = a[i];
    float dtr[3];
#pragma unroll
    for (int r = 0; r < 3; r++) {
        float s = 0.f;
#pragma unroll
        for (int k = 0; k < 6; k++) s += ang[k] * Wx[r * 6 + k];
        dtr[r] = s;
    }
    float* rec = sd + (size_t)gid * SDS;
    float dtv[6];
#pragma unroll
    for (int i = 0; i < 6; i++) {
        float x = bdt[i];
#pragma unroll
        for (int r = 0; r < 3; r++) x += dtr[r] * Wdt[i * 3 + r];
        float sp = (x > 15.f) ? x : log1pf(expf(x));
        dtv[i] = tanhf(sp) * PI_F;
        rec[i] = dtv[i];
        float th = ang[i] * dtv[i];
        rec[6 + i]  = cosf(th);
        rec[12 + i] = sinf(th);
    }
    float C[6];
#pragma unroll
    for (int i = 0; i < 6; i++) {
        float s = 0.f;
#pragma unroll
        for (int k = 0; k < 6; k++) s += ang[k] * Wx[(9 + i) * 6 + k];
        C[i] = s;
    }
#pragma unroll
    for (int j = 0; j < 18; j++) {
        float s = 0.f;
#pragma unroll
        for (int i = 0; i < 6; i++) s += C[i] * Wc[j * 6 + i];
        rec[18 + j] = s;
        rec[36 + j] = D[j] * ang[j % 6];
    }
}

// ---------------------------------------------------------------------------
// umat_kernel: U[a][col] for the fixed 2-layer ansatz (R2-verified gate chain).
// ---------------------------------------------------------------------------
__global__ __launch_bounds__(64) void umat_kernel(const float* __restrict__ cp,
                                                  float2* __restrict__ um)
{
    const int lane = threadIdx.x;
    const int col = blockIdx.x;
    int bitv[6];
#pragma unroll
    for (int i = 0; i < 6; i++) bitv[i] = (lane >> (5 - i)) & 1;

    float qc[2][3][8], rc[2][6][4];
#pragma unroll
    for (int l = 0; l < 2; l++) {
        float g00r[6], g00i[6], g01r[6], g01i[6], g10r[6], g10i[6], g11r[6], g11i[6];
#pragma unroll
        for (int i = 0; i < 6; i++) {
            float ax = cp[l * 30 + i * 3 + 0];
            float ay = cp[l * 30 + i * 3 + 1];
            float az = cp[l * 30 + i * 3 + 2];
            float ca = cosf(0.5f * ax), sa = sinf(0.5f * ax);
            float cb = cosf(0.5f * ay), sb = sinf(0.5f * ay);
            float cg = cosf(0.5f * az), sg = sinf(0.5f * az);
            float m00r = cb * ca, m00i =  sb * sa;
            float m01r = -sb * ca, m01i = -cb * sa;
            float m10r =  sb * ca, m10i = -cb * sa;
            float m11r =  cb * ca, m11i = -sb * sa;
            g00r[i] = cg * m00r + sg * m00i; g00i[i] = cg * m00i - sg * m00r;
            g01r[i] = cg * m01r + sg * m01i; g01i[i] = cg * m01i - sg * m01r;
            g10r[i] = cg * m10r - sg * m10i; g10i[i] = cg * m10i + sg * m10r;
            g11r[i] = cg * m11r - sg * m11i; g11i[i] = cg * m11i + sg * m11r;
        }
#pragma unroll
        for (int pp = 0; pp < 3; pp++) {
            int aq = 2 * pp, bq = 2 * pp + 1;
            float dar = bitv[aq] ? g11r[aq] : g00r[aq], dai = bitv[aq] ? g11i[aq] : g00i[aq];
            float oar = bitv[aq] ? g10r[aq] : g01r[aq], oai = bitv[aq] ? g10i[aq] : g01i[aq];
            float dbr = bitv[bq] ? g11r[bq] : g00r[bq], dbi = bitv[bq] ? g11i[bq] : g00i[bq];
            float obr = bitv[bq] ? g10r[bq] : g01r[bq], obi = bitv[bq] ? g10i[bq] : g01i[bq];
            qc[l][pp][0] = dar * dbr - dai * dbi;  qc[l][pp][1] = dar * dbi + dai * dbr;
            qc[l][pp][2] = oar * dbr - oai * dbi;  qc[l][pp][3] = oar * dbi + oai * dbr;
            qc[l][pp][4] = dar * obr - dai * obi;  qc[l][pp][5] = dar * obi + dai * obr;
            qc[l][pp][6] = oar * obr - oai * obi;  qc[l][pp][7] = oar * obi + oai * obr;
        }
        const int Aq[6] = {0, 2, 4, 5, 3, 1};
        const int Bq[6] = {1, 3, 5, 4, 2, 0};
#pragma unroll
        for (int o = 0; o < 6; o++) {
            float tha = (o < 3) ? cp[l * 30 + 18 + 2 * o]     : cp[l * 30 + 24 + 2 * (o - 3)];
            float thb = (o < 3) ? cp[l * 30 + 18 + 2 * o + 1] : cp[l * 30 + 24 + 2 * (o - 3) + 1];
            float ca = cosf(0.5f * tha), sa = sinf(0.5f * tha);
            float cb = cosf(0.5f * thb), sb = sinf(0.5f * thb);
            int ba = bitv[Aq[o]], bb = bitv[Bq[o]];
            float mx0 = ba ? ca : 1.f, sae = ba ? sa : 0.f;
            float ny0 = bb ? cb : 1.f, sbe = bb ? sb : 0.f;
            rc[l][o][0] = ny0 * mx0; rc[l][o][1] = -ny0 * sae;
            rc[l][o][2] = -mx0 * sbe; rc[l][o][3] = -sae * sbe;
        }
    }

    float re = (lane == col) ? 1.f : 0.f;
    float im = 0.f;
    auto p1q = [&](int mi, int mj, const float* c) {
        float ar = __shfl_xor(re, mi, 64), ai = __shfl_xor(im, mi, 64);
        float br = __shfl_xor(re, mj, 64), bi = __shfl_xor(im, mj, 64);
        float cr = __shfl_xor(re, mi | mj, 64), ci = __shfl_xor(im, mi | mj, 64);
        float nr, ni;
        cmul4(c, re, im, ar, ai, br, bi, cr, ci, nr, ni);
        re = nr; im = ni;
    };
    auto rng = [&](int mb, int mc, const float* c) {
        float br = __shfl_xor(re, mb, 64), bi = __shfl_xor(im, mb, 64);
        float cr = __shfl_xor(re, mc, 64), ci = __shfl_xor(im, mc, 64);
        float dr = __shfl_xor(re, mb | mc, 64), di = __shfl_xor(im, mb | mc, 64);
        float nr, ni;
        ringapply(c, re, im, br, bi, cr, ci, dr, di, nr, ni);
        re = nr; im = ni;
    };
#pragma unroll
    for (int l = 0; l < 2; l++) {
        p1q(32, 16, qc[l][0]);
        p1q(8, 4, qc[l][1]);
        p1q(2, 1, qc[l][2]);
        rng(16, 8, rc[l][0]);
        rng(4, 2, rc[l][1]);
        rng(1, 32, rc[l][2]);
        rng(2, 4, rc[l][3]);
        rng(8, 16, rc[l][4]);
        rng(32, 1, rc[l][5]);
    }
    um[(size_t)lane * 64 + col] = make_float2(re, im);
}

// ---------------------------------------------------------------------------
// step_kernel: TWO independent batch chains per block (512 threads, 8 waves).
// Waves 0-3 = chain A, waves 4-7 = chain B; wave w of each chain lands on
// SIMD w -> 2 independent waves per SIMD hide each other's dependency stalls.
// Per-chain body is R7's proven 4-wave / 2-barrier structure, verbatim.
// ---------------------------------------------------------------------------
__global__ __launch_bounds__(512, 1) void step_kernel(
    const float* __restrict__ sd, const float* __restrict__ pc,
    const float* __restrict__ qp, const float2* __restrict__ um,
    float* __restrict__ out)
{
    __shared__ float2 sPart[2][4][64];              // [chain][wave][lane]
    __shared__ __align__(16) float sZX[2][12];      // [chain][Z0..5 X0..5]
    const int tid = threadIdx.x;
    const int chain = tid >> 8;
    const int wave = (tid >> 6) & 3;
    const int lane = tid & 63;
    const int b = blockIdx.x * 2 + chain;

    int bitv[6];
#pragma unroll
    for (int i = 0; i < 6; i++) bitv[i] = (lane >> (5 - i)) & 1;
    int sflip[6];
#pragma unroll
    for (int q = 0; q < 6; q++) sflip[q] = bitv[q] ? (int)0x80000000 : 0;

    // U column-chunk rows: wave w owns columns [16w, 16w+16)
    const int jbase = wave * 16;
    float2 row[16];
#pragma unroll
    for (int jj = 0; jj < 16; jj++) row[jj] = um[(size_t)lane * 64 + jbase + jj];

    // QSVT collapse: per-lane phase coefs + permuted product-state selects
    float A[6], sel[6];
    {
        int x1 = permf(lane), x2 = permf(x1), x3 = permf(x2), x4 = permf(x3);
#pragma unroll
        for (int i = 0; i < 6; i++) {
            float u0 = pc[0] * PI_F * qp[0 * 6 + i];
            float u1 = pc[1] * PI_F * qp[1 * 6 + i];
            float u2 = pc[2] * PI_F * qp[2 * 6 + i];
            float u3 = pc[3] * PI_F;
            float t1 = ((x1 >> (5 - i)) & 1) ? 0.5f : -0.5f;
            float t2 = ((x2 >> (5 - i)) & 1) ? 0.5f : -0.5f;
            float t3 = ((x3 >> (5 - i)) & 1) ? 0.5f : -0.5f;
            float t4 = ((x4 >> (5 - i)) & 1) ? 0.5f : -0.5f;
            A[i] = u3 * t1 + u2 * t2 + u1 * t3 + u0 * t4;
            sel[i] = (float)((x4 >> (5 - i)) & 1);
        }
    }

    const float* sdb = sd + (size_t)b * SEQ * SDS;
    float* outb = out + (size_t)b * SEQ * 18;

    float h0 = 0.f, h1 = 0.f, h2 = 0.f, h3 = 0.f, h4 = 0.f, h5 = 0.f;

    // software-pipelined record fields: dt[6], cos[6], sin[6]
    float cd[18], nd[18];
#pragma unroll
    for (int k = 0; k < 18; k++) cd[k] = sdb[k];

    for (int t = 0; t < SEQ; t++) {
        const float* r  = sdb + (size_t)t * SDS;
        const float* rn = sdb + (size_t)((t + 1 < SEQ) ? t + 1 : t) * SDS;
        // prefetch next record (stays in flight across lgkm-only barriers)
#pragma unroll
        for (int k = 0; k < 18; k++) nd[k] = rn[k];

        // ---- QSVT phase (h-independent) ----
        float phi = A[0]*cd[0] + A[1]*cd[1] + A[2]*cd[2] + A[3]*cd[3] + A[4]*cd[4] + A[5]*cd[5];
        float sph, cph;
        __sincosf(phi, &sph, &cph);

        // ---- product state RY(h)|0..0>, pre-permuted via sel bits ----
        float ss0, cc0, ss1, cc1, ss2, cc2, ss3, cc3, ss4, cc4, ss5, cc5;
        __sincosf(0.5f * h0, &ss0, &cc0);
        __sincosf(0.5f * h1, &ss1, &cc1);
        __sincosf(0.5f * h2, &ss2, &cc2);
        __sincosf(0.5f * h3, &ss3, &cc3);
        __sincosf(0.5f * h4, &ss4, &cc4);
        __sincosf(0.5f * h5, &ss5, &cc5);
        float f0 = fmaf(sel[0], ss0 - cc0, cc0);
        float f1 = fmaf(sel[1], ss1 - cc1, cc1);
        float f2 = fmaf(sel[2], ss2 - cc2, cc2);
        float f3 = fmaf(sel[3], ss3 - cc3, cc3);
        float f4 = fmaf(sel[4], ss4 - cc4, cc4);
        float f5 = fmaf(sel[5], ss5 - cc5, cc5);
        float prod = ((f0 * f1) * (f2 * f3)) * (f4 * f5);
        float pr = prod * cph, pi = prod * sph;

        // ---- partial matvec over this wave's 16 columns ----
        float ar0 = 0.f, ai0 = 0.f, ar1 = 0.f, ai1 = 0.f;
#pragma unroll
        for (int jj = 0; jj < 16; jj += 2) {
            float sr0 = rdlv(pr, jbase + jj);
            float si0 = rdlv(pi, jbase + jj);
            float sr1 = rdlv(pr, jbase + jj + 1);
            float si1 = rdlv(pi, jbase + jj + 1);
            ar0 = fmaf(row[jj].x, sr0, ar0);
            ar0 = fmaf(-row[jj].y, si0, ar0);
            ai0 = fmaf(row[jj].x, si0, ai0);
            ai0 = fmaf(row[jj].y, sr0, ai0);
            ar1 = fmaf(row[jj + 1].x, sr1, ar1);
            ar1 = fmaf(-row[jj + 1].y, si1, ar1);
            ai1 = fmaf(row[jj + 1].x, si1, ai1);
            ai1 = fmaf(row[jj + 1].y, sr1, ai1);
        }
        sPart[chain][wave][lane] = make_float2(ar0 + ar1, ai0 + ai1);
        wg_barrier_lds();   // barrier A (syncs both chains; identical structure)
        float2 q0v = sPart[chain][0][lane], q1v = sPart[chain][1][lane];
        float2 q2v = sPart[chain][2][lane], q3v = sPart[chain][3][lane];
        float re = (q0v.x + q1v.x) + (q2v.x + q3v.x);
        float im = (q0v.y + q1v.y) + (q2v.y + q3v.y);

        // ---- split reductions (R7 layout) ----
        if (wave == 0) {
            float p = re * re + im * im;
            float Z0 = redsum64(xorf(p, sflip[0]));
            float Z1 = redsum64(xorf(p, sflip[1]));
            float Z2 = redsum64(xorf(p, sflip[2]));
            float Z3 = redsum64(xorf(p, sflip[3]));
            float Z4 = redsum64(xorf(p, sflip[4]));
            float Z5 = redsum64(xorf(p, sflip[5]));
            if (lane == 0) {
                sZX[chain][0] = Z0; sZX[chain][1] = Z1; sZX[chain][2] = Z2;
                sZX[chain][3] = Z3; sZX[chain][4] = Z4; sZX[chain][5] = Z5;
            }
        } else if (wave == 1) {
            float g0r = shxm<32>(re), g0i = shxm<32>(im);   // q0
            float g1r = shxm<16>(re), g1i = shxm<16>(im);   // q1
            float X0 = redsum64(fmaf(re, g0r, im * g0i));
            float X1 = redsum64(fmaf(re, g1r, im * g1i));
            float Y0 = redsum64(xorf(re * g0i - im * g0r, sflip[0]));
            float Y1 = redsum64(xorf(re * g1i - im * g1r, sflip[1]));
            if (lane == 0) { sZX[chain][6] = X0; sZX[chain][7] = X1; }
            if (lane == 0) {
                // stash Y0,Y1 via LDS (reuse sPart slot after reads complete):
                sPart[chain][0][0].x = Y0; sPart[chain][0][0].y = Y1;
            }
        } else if (wave == 2) {
            float g2r = shxm<8>(re), g2i = shxm<8>(im);     // q2
            float g3r = shxm<4>(re), g3i = shxm<4>(im);     // q3
            float X2 = redsum64(fmaf(re, g2r, im * g2i));
            float X3 = redsum64(fmaf(re, g3r, im * g3i));
            float Y2 = redsum64(xorf(re * g2i - im * g2r, sflip[2]));
            float Y3 = redsum64(xorf(re * g3i - im * g3r, sflip[3]));
            if (lane == 0) {
                sZX[chain][8] = X2; sZX[chain][9] = X3;
                sPart[chain][1][0].x = Y2; sPart[chain][1][0].y = Y3;
            }
        } else {
            float g4r = shxm<2>(re), g4i = shxm<2>(im);     // q4
            float g5r = shxm<1>(re), g5i = shxm<1>(im);     // q5
            float X4 = redsum64(fmaf(re, g4r, im * g4i));
            float X5 = redsum64(fmaf(re, g5r, im * g5i));
            float Y4 = redsum64(xorf(re * g4i - im * g4r, sflip[4]));
            float Y5 = redsum64(xorf(re * g5i - im * g5r, sflip[5]));
            if (lane == 0) {
                sZX[chain][10] = X4; sZX[chain][11] = X5;
                sPart[chain][2][0].x = Y4; sPart[chain][2][0].y = Y5;
            }
        }
        wg_barrier_lds();   // barrier B

        // ---- all waves: vectorized scalar broadcast, assemble h ----
        float4 v0 = ((const float4*)sZX[chain])[0];   // Z0..Z3
        float4 v1 = ((const float4*)sZX[chain])[1];   // Z4 Z5 X0 X1
        float4 v2 = ((const float4*)sZX[chain])[2];   // X2..X5
        float Zv[6] = {v0.x, v0.y, v0.z, v0.w, v1.x, v1.y};
        float Xv[6] = {v1.z, v1.w, v2.x, v2.y, v2.z, v2.w};
        h0 = cd[6]  * Zv[0] - cd[12] * Xv[0];
        h1 = cd[7]  * Zv[1] - cd[13] * Xv[1];
        h2 = cd[8]  * Zv[2] - cd[14] * Xv[2];
        h3 = cd[9]  * Zv[3] - cd[15] * Xv[3];
        h4 = cd[10] * Zv[4] - cd[16] * Xv[4];
        h5 = cd[11] * Zv[5] - cd[17] * Xv[5];

        // ---- stores (global, fire-and-forget) ----
        if (wave == 0 && lane == 0) {
            float* o = outb + (size_t)t * 18;
            float hh[6] = {h0, h1, h2, h3, h4, h5};
#pragma unroll
            for (int q = 0; q < 6; q++) o[12 + q] = fmaf(r[30 + q], hh[q], r[48 + q]);
        }
        if (wave == 3 && lane == 0) {
            float* o = outb + (size_t)t * 18;
            float2 y01 = sPart[chain][0][0];
            float2 y23 = sPart[chain][1][0];
            float2 y45 = sPart[chain][2][0];
            float Yv[6] = {y01.x, y01.y, y23.x, y23.y, y45.x, y45.y};
#pragma unroll
            for (int q = 0; q < 6; q++) {
                float px = cd[6 + q] * Xv[q] + cd[12 + q] * Zv[q];
                o[q]     = fmaf(r[18 + q], px, r[36 + q]);
                o[6 + q] = fmaf(r[24 + q], Yv[q], r[42 + q]);
            }
        }

        // rotate pipelined record
#pragma unroll
        for (int k = 0; k < 18; k++) cd[k] = nd[k];
    }
}

// ---------------------------------------------------------------------------
extern "C" void kernel_launch(void* const* d_in, const int* in_sizes, int n_in,
                              void* d_out, int out_size, void* d_ws, size_t ws_size,
                              hipStream_t stream) {
    const float* angles = (const float*)d_in[0];
    const float* Wx     = (const float*)d_in[1];
    const float* Wdt    = (const float*)d_in[2];
    const float* bdt    = (const float*)d_in[3];
    const float* pc     = (const float*)d_in[4];
    const float* qp     = (const float*)d_in[5];
    const float* cp     = (const float*)d_in[6];
    const float* D      = (const float*)d_in[7];
    const float* Wc     = (const float*)d_in[8];
    float* sd  = (float*)d_ws;                                // 28.3 MB
    float2* um = (float2*)(sd + (size_t)BATCH * SEQ * SDS);   // +32 KB
    float* out = (float*)d_out;

    umat_kernel<<<64, 64, 0, stream>>>(cp, um);
    prep_kernel<<<(BATCH * SEQ) / 256, 256, 0, stream>>>(angles, Wx, Wdt, bdt, D, Wc, sd);
    step_kernel<<<BATCH / 2, 512, 0, stream>>>(sd, pc, qp, um, out);
}

// Round 12
// 719.934 us; speedup vs baseline: 1.3972x; 1.3546x over previous
//
#include <hip/hip_runtime.h>
#include <math.h>

#define BATCH 256
#define SEQ 512
#define SDS 54            // floats per (b,t) record: dt[6] cos[6] sin[6] Cc[18] term[18]
#define PI_F 3.14159265358979323846f
#define INV2PI 0.15915494309189535f

// ---- cross-lane helpers -----------------------------------------------------
template<int CTRL>
__device__ __forceinline__ float fdpp(float v) {
    return __int_as_float(__builtin_amdgcn_mov_dpp(__float_as_int(v), CTRL, 0xF, 0xF, true));
}
template<int L>
__device__ __forceinline__ float rdl(float v) {
    return __int_as_float(__builtin_amdgcn_readlane(__float_as_int(v), L));
}
__device__ __forceinline__ float rdlv(float v, int l) {
    return __int_as_float(__builtin_amdgcn_readlane(__float_as_int(v), l));
}
template<int M>
__device__ __forceinline__ float shxm(float v) {
    if constexpr (M == 1)       return fdpp<0xB1>(v);
    else if constexpr (M == 2)  return fdpp<0x4E>(v);
    else if constexpr (M == 8)  return fdpp<0x128>(v);
    else if constexpr (M == 32) return __shfl_xor(v, 32, 64);
    else return __int_as_float(__builtin_amdgcn_ds_swizzle(__float_as_int(v), (M << 10) | 0x1F));
}
// full 64-lane sum (uniform result): DPP row_ror rotate-adds + readlane combine
__device__ __forceinline__ float redsum64(float v) {
    v += fdpp<0x128>(v);
    v += fdpp<0x124>(v);
    v += fdpp<0x122>(v);
    v += fdpp<0x121>(v);
    return (rdl<0>(v) + rdl<16>(v)) + (rdl<32>(v) + rdl<48>(v));
}
__device__ __forceinline__ float xorf(float v, int m) {
    return __int_as_float(__float_as_int(v) ^ m);
}
// native HW sincos: v_sin/v_cos take input in revolutions (sin(S0*2pi)).
// All loop angles are small (|x| <= ~2 rad) — HW-exact domain; accuracy
// verified end-to-end in R9 (absmax identical to ocml path: 0.015625).
__device__ __forceinline__ void nsincos(float x, float& s, float& c) {
    float r = x * INV2PI;
    s = __builtin_amdgcn_sinf(r);
    c = __builtin_amdgcn_cosf(r);
}
// Workgroup barrier with LDS-only drain (lgkmcnt(0)); global ops stay in flight.
// 0xC07F = vmcnt(63) expcnt(7) lgkmcnt(0) in gfx9 encoding. Verified R7.
__device__ __forceinline__ void wg_barrier_lds() {
    __builtin_amdgcn_sched_barrier(0);
    __builtin_amdgcn_s_waitcnt(0xC07F);
    __builtin_amdgcn_s_barrier();
    __builtin_amdgcn_sched_barrier(0);
}
// QSVT per-degree CNOT-block permutation (GF(2)-linear) — verified R1-R11
__device__ __forceinline__ int permf(int x) {
    const int cs[11] = {0,1,2,3,4,5,5,4,3,2,1};
    const int ts[11] = {1,2,3,4,5,0,4,3,2,1,0};
#pragma unroll
    for (int k = 10; k >= 0; k--) {
        int cb = (x >> (5 - cs[k])) & 1;
        x ^= cb << (5 - ts[k]);
    }
    return x;
}
__device__ __forceinline__ void cmul4(const float* c,
    float vr, float vi, float ar, float ai, float br, float bi, float cr, float ci,
    float& nr, float& ni) {
    nr = c[0]*vr - c[1]*vi + c[2]*ar - c[3]*ai + c[4]*br - c[5]*bi + c[6]*cr - c[7]*ci;
    ni = c[0]*vi + c[1]*vr + c[2]*ai + c[3]*ar + c[4]*bi + c[5]*br + c[6]*ci + c[7]*cr;
}
__device__ __forceinline__ void ringapply(const float* rc,
    float vr, float vi, float br, float bi, float cr, float ci, float dr, float di,
    float& nr, float& ni) {
    nr = rc[0]*vr - rc[1]*bi - rc[2]*ci + rc[3]*dr;
    ni = rc[0]*vi + rc[1]*br + rc[2]*cr + rc[3]*di;
}

// ---------------------------------------------------------------------------
__global__ __launch_bounds__(256) void prep_kernel(
    const float* __restrict__ angles, const float* __restrict__ Wx,
    const float* __restrict__ Wdt, const float* __restrict__ bdt,
    const float* __restrict__ D, const float* __restrict__ Wc,
    float* __restrict__ sd)
{
    int gid = blockIdx.x * blockDim.x + threadIdx.x;
    if (gid >= BATCH * SEQ) return;
    const float* a = angles + (size_t)gid * 6;
    float ang[6];
#pragma unroll
    for (int i = 0; i < 6; i++) ang[i] = a[i];
    float dtr[3];
#pragma unroll
    for (int r = 0; r < 3; r++) {
        float s = 0.f;
#pragma unroll
        for (int k = 0; k < 6; k++) s += ang[k] * Wx[r * 6 + k];
        dtr[r] = s;
    }
    float* rec = sd + (size_t)gid * SDS;
    float dtv[6];
#pragma unroll
    for (int i = 0; i < 6; i++) {
        float x = bdt[i];
#pragma unroll
        for (int r = 0; r < 3; r++) x += dtr[r] * Wdt[i * 3 + r];
        float sp = (x > 15.f) ? x : log1pf(expf(x));
        dtv[i] = tanhf(sp) * PI_F;
        rec[i] = dtv[i];
        float th = ang[i] * dtv[i];
        rec[6 + i]  = cosf(th);
        rec[12 + i] = sinf(th);
    }
    float C[6];
#pragma unroll
    for (int i = 0; i < 6; i++) {
        float s = 0.f;
#pragma unroll
        for (int k = 0; k < 6; k++) s += ang[k] * Wx[(9 + i) * 6 + k];
        C[i] = s;
    }
#pragma unroll
    for (int j = 0; j < 18; j++) {
        float s = 0.f;
#pragma unroll
        for (int i = 0; i < 6; i++) s += C[i] * Wc[j * 6 + i];
        rec[18 + j] = s;
        rec[36 + j] = D[j] * ang[j % 6];
    }
}

// ---------------------------------------------------------------------------
// umat_kernel: U[a][col] for the fixed 2-layer ansatz (R2-verified gate chain).
// ---------------------------------------------------------------------------
__global__ __launch_bounds__(64) void umat_kernel(const float* __restrict__ cp,
                                                  float2* __restrict__ um)
{
    const int lane = threadIdx.x;
    const int col = blockIdx.x;
    int bitv[6];
#pragma unroll
    for (int i = 0; i < 6; i++) bitv[i] = (lane >> (5 - i)) & 1;

    float qc[2][3][8], rc[2][6][4];
#pragma unroll
    for (int l = 0; l < 2; l++) {
        float g00r[6], g00i[6], g01r[6], g01i[6], g10r[6], g10i[6], g11r[6], g11i[6];
#pragma unroll
        for (int i = 0; i < 6; i++) {
            float ax = cp[l * 30 + i * 3 + 0];
            float ay = cp[l * 30 + i * 3 + 1];
            float az = cp[l * 30 + i * 3 + 2];
            float ca = cosf(0.5f * ax), sa = sinf(0.5f * ax);
            float cb = cosf(0.5f * ay), sb = sinf(0.5f * ay);
            float cg = cosf(0.5f * az), sg = sinf(0.5f * az);
            float m00r = cb * ca, m00i =  sb * sa;
            float m01r = -sb * ca, m01i = -cb * sa;
            float m10r =  sb * ca, m10i = -cb * sa;
            float m11r =  cb * ca, m11i = -sb * sa;
            g00r[i] = cg * m00r + sg * m00i; g00i[i] = cg * m00i - sg * m00r;
            g01r[i] = cg * m01r + sg * m01i; g01i[i] = cg * m01i - sg * m01r;
            g10r[i] = cg * m10r - sg * m10i; g10i[i] = cg * m10i + sg * m10r;
            g11r[i] = cg * m11r - sg * m11i; g11i[i] = cg * m11i + sg * m11r;
        }
#pragma unroll
        for (int pp = 0; pp < 3; pp++) {
            int aq = 2 * pp, bq = 2 * pp + 1;
            float dar = bitv[aq] ? g11r[aq] : g00r[aq], dai = bitv[aq] ? g11i[aq] : g00i[aq];
            float oar = bitv[aq] ? g10r[aq] : g01r[aq], oai = bitv[aq] ? g10i[aq] : g01i[aq];
            float dbr = bitv[bq] ? g11r[bq] : g00r[bq], dbi = bitv[bq] ? g11i[bq] : g00i[bq];
            float obr = bitv[bq] ? g10r[bq] : g01r[bq], obi = bitv[bq] ? g10i[bq] : g01i[bq];
            qc[l][pp][0] = dar * dbr - dai * dbi;  qc[l][pp][1] = dar * dbi + dai * dbr;
            qc[l][pp][2] = oar * dbr - oai * dbi;  qc[l][pp][3] = oar * dbi + oai * dbr;
            qc[l][pp][4] = dar * obr - dai * obi;  qc[l][pp][5] = dar * obi + dai * obr;
            qc[l][pp][6] = oar * obr - oai * obi;  qc[l][pp][7] = oar * obi + oai * obr;
        }
        const int Aq[6] = {0, 2, 4, 5, 3, 1};
        const int Bq[6] = {1, 3, 5, 4, 2, 0};
#pragma unroll
        for (int o = 0; o < 6; o++) {
            float tha = (o < 3) ? cp[l * 30 + 18 + 2 * o]     : cp[l * 30 + 24 + 2 * (o - 3)];
            float thb = (o < 3) ? cp[l * 30 + 18 + 2 * o + 1] : cp[l * 30 + 24 + 2 * (o - 3) + 1];
            float ca = cosf(0.5f * tha), sa = sinf(0.5f * tha);
            float cb = cosf(0.5f * thb), sb = sinf(0.5f * thb);
            int ba = bitv[Aq[o]], bb = bitv[Bq[o]];
            float mx0 = ba ? ca : 1.f, sae = ba ? sa : 0.f;
            float ny0 = bb ? cb : 1.f, sbe = bb ? sb : 0.f;
            rc[l][o][0] = ny0 * mx0; rc[l][o][1] = -ny0 * sae;
            rc[l][o][2] = -mx0 * sbe; rc[l][o][3] = -sae * sbe;
        }
    }

    float re = (lane == col) ? 1.f : 0.f;
    float im = 0.f;
    auto p1q = [&](int mi, int mj, const float* c) {
        float ar = __shfl_xor(re, mi, 64), ai = __shfl_xor(im, mi, 64);
        float br = __shfl_xor(re, mj, 64), bi = __shfl_xor(im, mj, 64);
        float cr = __shfl_xor(re, mi | mj, 64), ci = __shfl_xor(im, mi | mj, 64);
        float nr, ni;
        cmul4(c, re, im, ar, ai, br, bi, cr, ci, nr, ni);
        re = nr; im = ni;
    };
    auto rng = [&](int mb, int mc, const float* c) {
        float br = __shfl_xor(re, mb, 64), bi = __shfl_xor(im, mb, 64);
        float cr = __shfl_xor(re, mc, 64), ci = __shfl_xor(im, mc, 64);
        float dr = __shfl_xor(re, mb | mc, 64), di = __shfl_xor(im, mb | mc, 64);
        float nr, ni;
        ringapply(c, re, im, br, bi, cr, ci, dr, di, nr, ni);
        re = nr; im = ni;
    };
#pragma unroll
    for (int l = 0; l < 2; l++) {
        p1q(32, 16, qc[l][0]);
        p1q(8, 4, qc[l][1]);
        p1q(2, 1, qc[l][2]);
        rng(16, 8, rc[l][0]);
        rng(4, 2, rc[l][1]);
        rng(1, 32, rc[l][2]);
        rng(2, 4, rc[l][3]);
        rng(8, 16, rc[l][4]);
        rng(32, 1, rc[l][5]);
    }
    um[(size_t)lane * 64 + col] = make_float2(re, im);
}

// ---------------------------------------------------------------------------
// step_kernel: R7's proven 4-wave / 2-barrier structure, VERBATIM, with one
// change: in-loop __sincosf -> native v_sin/v_cos (single-variable test).
// ---------------------------------------------------------------------------
__global__ __launch_bounds__(256, 1) void step_kernel(
    const float* __restrict__ sd, const float* __restrict__ pc,
    const float* __restrict__ qp, const float2* __restrict__ um,
    float* __restrict__ out)
{
    __shared__ float2 sPart[4][64];
    __shared__ __align__(16) float sZX[12];    // Z0..5, X0..5
    __shared__ float sY[6];
    const int tid = threadIdx.x;
    const int wave = tid >> 6;
    const int lane = tid & 63;
    const int b = blockIdx.x;

    int bitv[6];
#pragma unroll
    for (int i = 0; i < 6; i++) bitv[i] = (lane >> (5 - i)) & 1;
    int sflip[6];
#pragma unroll
    for (int q = 0; q < 6; q++) sflip[q] = bitv[q] ? (int)0x80000000 : 0;

    // U column-chunk rows: wave w owns columns [16w, 16w+16)
    const int jbase = wave * 16;
    float2 row[16];
#pragma unroll
    for (int jj = 0; jj < 16; jj++) row[jj] = um[(size_t)lane * 64 + jbase + jj];

    // QSVT collapse: per-lane phase coefs + permuted product-state selects
    float A[6], sel[6];
    {
        int x1 = permf(lane), x2 = permf(x1), x3 = permf(x2), x4 = permf(x3);
#pragma unroll
        for (int i = 0; i < 6; i++) {
            float u0 = pc[0] * PI_F * qp[0 * 6 + i];
            float u1 = pc[1] * PI_F * qp[1 * 6 + i];
            float u2 = pc[2] * PI_F * qp[2 * 6 + i];
            float u3 = pc[3] * PI_F;
            float t1 = ((x1 >> (5 - i)) & 1) ? 0.5f : -0.5f;
            float t2 = ((x2 >> (5 - i)) & 1) ? 0.5f : -0.5f;
            float t3 = ((x3 >> (5 - i)) & 1) ? 0.5f : -0.5f;
            float t4 = ((x4 >> (5 - i)) & 1) ? 0.5f : -0.5f;
            A[i] = u3 * t1 + u2 * t2 + u1 * t3 + u0 * t4;
            sel[i] = (float)((x4 >> (5 - i)) & 1);
        }
    }

    const float* sdb = sd + (size_t)b * SEQ * SDS;
    float* outb = out + (size_t)b * SEQ * 18;

    float h0 = 0.f, h1 = 0.f, h2 = 0.f, h3 = 0.f, h4 = 0.f, h5 = 0.f;

    // software-pipelined record fields: d[6], ct[6], st[6]
    float cd[18], nd[18];
#pragma unroll
    for (int k = 0; k < 18; k++) cd[k] = sdb[k];

    for (int t = 0; t < SEQ; t++) {
        const float* r  = sdb + (size_t)t * SDS;
        const float* rn = sdb + (size_t)((t + 1 < SEQ) ? t + 1 : t) * SDS;
        // prefetch next record (stays in flight: barriers do NOT drain vmcnt)
#pragma unroll
        for (int k = 0; k < 18; k++) nd[k] = rn[k];

        // ---- QSVT phase (h-independent) ----
        float phi = A[0]*cd[0] + A[1]*cd[1] + A[2]*cd[2] + A[3]*cd[3] + A[4]*cd[4] + A[5]*cd[5];
        float sph, cph;
        nsincos(phi, sph, cph);

        // ---- product state RY(h)|0..0>, pre-permuted via sel bits ----
        float ss0, cc0, ss1, cc1, ss2, cc2, ss3, cc3, ss4, cc4, ss5, cc5;
        nsincos(0.5f * h0, ss0, cc0);
        nsincos(0.5f * h1, ss1, cc1);
        nsincos(0.5f * h2, ss2, cc2);
        nsincos(0.5f * h3, ss3, cc3);
        nsincos(0.5f * h4, ss4, cc4);
        nsincos(0.5f * h5, ss5, cc5);
        float f0 = fmaf(sel[0], ss0 - cc0, cc0);
        float f1 = fmaf(sel[1], ss1 - cc1, cc1);
        float f2 = fmaf(sel[2], ss2 - cc2, cc2);
        float f3 = fmaf(sel[3], ss3 - cc3, cc3);
        float f4 = fmaf(sel[4], ss4 - cc4, cc4);
        float f5 = fmaf(sel[5], ss5 - cc5, cc5);
        float prod = ((f0 * f1) * (f2 * f3)) * (f4 * f5);
        float pr = prod * cph, pi = prod * sph;

        // ---- partial matvec over this wave's 16 columns ----
        float ar0 = 0.f, ai0 = 0.f, ar1 = 0.f, ai1 = 0.f;
#pragma unroll
        for (int jj = 0; jj < 16; jj += 2) {
            float sr0 = rdlv(pr, jbase + jj);
            float si0 = rdlv(pi, jbase + jj);
            float sr1 = rdlv(pr, jbase + jj + 1);
            float si1 = rdlv(pi, jbase + jj + 1);
            ar0 = fmaf(row[jj].x, sr0, ar0);
            ar0 = fmaf(-row[jj].y, si0, ar0);
            ai0 = fmaf(row[jj].x, si0, ai0);
            ai0 = fmaf(row[jj].y, sr0, ai0);
            ar1 = fmaf(row[jj + 1].x, sr1, ar1);
            ar1 = fmaf(-row[jj + 1].y, si1, ar1);
            ai1 = fmaf(row[jj + 1].x, si1, ai1);
            ai1 = fmaf(row[jj + 1].y, sr1, ai1);
        }
        sPart[wave][lane] = make_float2(ar0 + ar1, ai0 + ai1);
        wg_barrier_lds();   // barrier A (LDS-only drain)
        float2 q0v = sPart[0][lane], q1v = sPart[1][lane];
        float2 q2v = sPart[2][lane], q3v = sPart[3][lane];
        float re = (q0v.x + q1v.x) + (q2v.x + q3v.x);
        float im = (q0v.y + q1v.y) + (q2v.y + q3v.y);

        // ---- reductions split by qubit across waves ----
        if (wave == 0) {
            float p = re * re + im * im;
            float Z0 = redsum64(xorf(p, sflip[0]));
            float Z1 = redsum64(xorf(p, sflip[1]));
            float Z2 = redsum64(xorf(p, sflip[2]));
            float Z3 = redsum64(xorf(p, sflip[3]));
            float Z4 = redsum64(xorf(p, sflip[4]));
            float Z5 = redsum64(xorf(p, sflip[5]));
            if (lane == 0) {
                sZX[0] = Z0; sZX[1] = Z1; sZX[2] = Z2;
                sZX[3] = Z3; sZX[4] = Z4; sZX[5] = Z5;
            }
        } else if (wave == 1) {
            float g0r = shxm<32>(re), g0i = shxm<32>(im);   // q0
            float g1r = shxm<16>(re), g1i = shxm<16>(im);   // q1
            float X0 = redsum64(fmaf(re, g0r, im * g0i));
            float X1 = redsum64(fmaf(re, g1r, im * g1i));
            float Y0 = redsum64(xorf(re * g0i - im * g0r, sflip[0]));
            float Y1 = redsum64(xorf(re * g1i - im * g1r, sflip[1]));
            if (lane == 0) { sZX[6] = X0; sZX[7] = X1; sY[0] = Y0; sY[1] = Y1; }
        } else if (wave == 2) {
            float g2r = shxm<8>(re), g2i = shxm<8>(im);     // q2
            float g3r = shxm<4>(re), g3i = shxm<4>(im);     // q3
            float X2 = redsum64(fmaf(re, g2r, im * g2i));
            float X3 = redsum64(fmaf(re, g3r, im * g3i));
            float Y2 = redsum64(xorf(re * g2i - im * g2r, sflip[2]));
            float Y3 = redsum64(xorf(re * g3i - im * g3r, sflip[3]));
            if (lane == 0) { sZX[8] = X2; sZX[9] = X3; sY[2] = Y2; sY[3] = Y3; }
        } else {
            float g4r = shxm<2>(re), g4i = shxm<2>(im);     // q4
            float g5r = shxm<1>(re), g5i = shxm<1>(im);     // q5
            float X4 = redsum64(fmaf(re, g4r, im * g4i));
            float X5 = redsum64(fmaf(re, g5r, im * g5i));
            float Y4 = redsum64(xorf(re * g4i - im * g4r, sflip[4]));
            float Y5 = redsum64(xorf(re * g5i - im * g5r, sflip[5]));
            if (lane == 0) { sZX[10] = X4; sZX[11] = X5; sY[4] = Y4; sY[5] = Y5; }
        }
        wg_barrier_lds();   // barrier B (LDS-only drain)

        // ---- all waves: vectorized scalar broadcast, assemble h ----
        float4 v0 = ((const float4*)sZX)[0];   // Z0..Z3
        float4 v1 = ((const float4*)sZX)[1];   // Z4 Z5 X0 X1
        float4 v2 = ((const float4*)sZX)[2];   // X2..X5
        float Zv[6] = {v0.x, v0.y, v0.z, v0.w, v1.x, v1.y};
        float Xv[6] = {v1.z, v1.w, v2.x, v2.y, v2.z, v2.w};
        h0 = cd[6]  * Zv[0] - cd[12] * Xv[0];
        h1 = cd[7]  * Zv[1] - cd[13] * Xv[1];
        h2 = cd[8]  * Zv[2] - cd[14] * Xv[2];
        h3 = cd[9]  * Zv[3] - cd[15] * Xv[3];
        h4 = cd[10] * Zv[4] - cd[16] * Xv[4];
        h5 = cd[11] * Zv[5] - cd[17] * Xv[5];

        // ---- stores (global, fire-and-forget; never drained by barriers) ----
        if (wave == 0 && lane == 0) {
            float* o = outb + (size_t)t * 18;
            float hh[6] = {h0, h1, h2, h3, h4, h5};
#pragma unroll
            for (int q = 0; q < 6; q++) o[12 + q] = fmaf(r[30 + q], hh[q], r[48 + q]);
        }
        if (wave == 3 && lane == 0) {
            float* o = outb + (size_t)t * 18;
#pragma unroll
            for (int q = 0; q < 6; q++) {
                float px = cd[6 + q] * Xv[q] + cd[12 + q] * Zv[q];
                o[q]     = fmaf(r[18 + q], px, r[36 + q]);
                o[6 + q] = fmaf(r[24 + q], sY[q], r[42 + q]);
            }
        }

        // rotate pipelined record
#pragma unroll
        for (int k = 0; k < 18; k++) cd[k] = nd[k];
    }
}

// ---------------------------------------------------------------------------
extern "C" void kernel_launch(void* const* d_in, const int* in_sizes, int n_in,
                              void* d_out, int out_size, void* d_ws, size_t ws_size,
                              hipStream_t stream) {
    const float* angles = (const float*)d_in[0];
    const float* Wx     = (const float*)d_in[1];
    const float* Wdt    = (const float*)d_in[2];
    const float* bdt    = (const float*)d_in[3];
    const float* pc     = (const float*)d_in[4];
    const float* qp     = (const float*)d_in[5];
    const float* cp     = (const float*)d_in[6];
    const float* D      = (const float*)d_in[7];
    const float* Wc     = (const float*)d_in[8];
    float* sd  = (float*)d_ws;                                // 28.3 MB
    float2* um = (float2*)(sd + (size_t)BATCH * SEQ * SDS);   // +32 KB
    float* out = (float*)d_out;

    umat_kernel<<<64, 64, 0, stream>>>(cp, um);
    prep_kernel<<<(BATCH * SEQ) / 256, 256, 0, stream>>>(angles, Wx, Wdt, bdt, D, Wc, sd);
    step_kernel<<<BATCH, 256, 0, stream>>>(sd, pc, qp, um, out);
}